// Round 3
// baseline (11.595 us; speedup 1.0000x reference)
//
#include <hip/hip_runtime.h>

// ResizeToSameSize: 12 fp32 planes -> (1,12,352,352) concat.
// out[c][y][x] = src_c[y >> shift_c][x >> shift_c]; shift_c in {0..5}.
// Scales are powers of two: 352 / {352,176,88,44,22,11} = {1,2,4,8,16,32}.
//
// One thread per float4 spatial position, handling ALL 12 channels:
// (y,x) decode amortized 12x, 484 waves total, straight-line code.

#define TARGET 352
#define PLANE (TARGET * TARGET)   // 123904 elements per channel

struct Ptrs { const float* p[12]; };

template <int SH, int SRCSZ>
__device__ __forceinline__ float4 fetch(const float* __restrict__ src, int e, int y, int x) {
    if constexpr (SH == 0) {
        return *reinterpret_cast<const float4*>(src + e);     // 16B coalesced copy
    } else if constexpr (SH == 1) {
        const float* row = src + (y >> 1) * SRCSZ;
        const float a = row[x >> 1];
        const float b = row[(x >> 1) + 1];
        return make_float4(a, a, b, b);
    } else {
        const float* row = src + (y >> SH) * SRCSZ;
        const float v = row[x >> SH];                         // 4 out-cols -> 1 src col
        return make_float4(v, v, v, v);
    }
}

__global__ __launch_bounds__(256) void resize_cat_kernel(Ptrs ptrs, float* __restrict__ out) {
    const int t = blockIdx.x * blockDim.x + threadIdx.x;      // float4 index in plane
    const int e = t * 4;                                      // element index in plane
    const int y = e / TARGET;
    const int x = e - y * TARGET;                             // multiple of 4

    // channel -> (shift, srcsz):
    // c:  0    1    2   3   4   5   6    7   8   9   10  11
    // sz: 352  176  88  44  22  11  176  88  44  22  11  176
    // sh: 0    1    2   3   4   5   1    2   3   4   5   1
    float4 v[12];
    v[0]  = fetch<0, TARGET>(ptrs.p[0],  e, y, x);
    v[1]  = fetch<1, 176  >(ptrs.p[1],  e, y, x);
    v[2]  = fetch<2, 88   >(ptrs.p[2],  e, y, x);
    v[3]  = fetch<3, 44   >(ptrs.p[3],  e, y, x);
    v[4]  = fetch<4, 22   >(ptrs.p[4],  e, y, x);
    v[5]  = fetch<5, 11   >(ptrs.p[5],  e, y, x);
    v[6]  = fetch<1, 176  >(ptrs.p[6],  e, y, x);
    v[7]  = fetch<2, 88   >(ptrs.p[7],  e, y, x);
    v[8]  = fetch<3, 44   >(ptrs.p[8],  e, y, x);
    v[9]  = fetch<4, 22   >(ptrs.p[9],  e, y, x);
    v[10] = fetch<5, 11   >(ptrs.p[10], e, y, x);
    v[11] = fetch<1, 176  >(ptrs.p[11], e, y, x);

    float* base = out + e;
#pragma unroll
    for (int c = 0; c < 12; ++c)
        *reinterpret_cast<float4*>(base + c * PLANE) = v[c];
}

extern "C" void kernel_launch(void* const* d_in, const int* in_sizes, int n_in,
                              void* d_out, int out_size, void* d_ws, size_t ws_size,
                              hipStream_t stream) {
    Ptrs ptrs;
    for (int i = 0; i < 12; ++i) ptrs.p[i] = (const float*)d_in[i];
    float* out = (float*)d_out;

    // plane float4 count = 123904/4 = 30976 = 121 * 256
    resize_cat_kernel<<<121, 256, 0, stream>>>(ptrs, out);
}

// Round 4
// 10.242 us; speedup vs baseline: 1.1321x; 1.1321x over previous
//
#include <hip/hip_runtime.h>

// ResizeToSameSize: 12 fp32 planes -> (1,12,352,352) concat.
// out[c][y][x] = src_c[y >> shift_c][x >> shift_c]; shift_c in {0..5}.
// Scales are powers of two: 352 / {352,176,88,44,22,11} = {1,2,4,8,16,32}.
//
// 6 channel-groups x 2 channels/thread (grid 121x6 = 726 blocks):
// enough blocks to cover all 256 CUs (~3 waves/CU) while amortizing the
// (y,x) decode 2x. Compile-time shifts -> straight-line code, no tables.

#define TARGET 352
#define PLANE (TARGET * TARGET)   // 123904 elements per channel

struct Ptrs { const float* p[12]; };

template <int SH, int SRCSZ>
__device__ __forceinline__ float4 fetch(const float* __restrict__ src, int e, int y, int x) {
    if constexpr (SH == 0) {
        return *reinterpret_cast<const float4*>(src + e);     // 16B coalesced copy
    } else if constexpr (SH == 1) {
        const float* row = src + (y >> 1) * SRCSZ;
        const float a = row[x >> 1];
        const float b = row[(x >> 1) + 1];
        return make_float4(a, a, b, b);
    } else {
        const float* row = src + (y >> SH) * SRCSZ;
        const float v = row[x >> SH];                         // 4 out-cols -> 1 src col
        return make_float4(v, v, v, v);
    }
}

// channel -> (shift, srcsz):
// c:  0    1    2   3   4   5   6    7   8   9   10  11
// sz: 352  176  88  44  22  11  176  88  44  22  11  176
// sh: 0    1    2   3   4   5   1    2   3   4   5   1

__global__ __launch_bounds__(256) void resize_cat_kernel(Ptrs ptrs, float* __restrict__ out) {
    const int g = blockIdx.y;                                 // channel pair 0..5
    const int t = blockIdx.x * blockDim.x + threadIdx.x;      // float4 index in plane
    const int e = t * 4;                                      // element index in plane
    const int y = e / TARGET;
    const int x = e - y * TARGET;                             // multiple of 4

    float4 v0, v1;
    switch (g) {
        case 0: v0 = fetch<0, TARGET>(ptrs.p[0],  e, y, x);
                v1 = fetch<1, 176  >(ptrs.p[1],  e, y, x); break;
        case 1: v0 = fetch<2, 88   >(ptrs.p[2],  e, y, x);
                v1 = fetch<3, 44   >(ptrs.p[3],  e, y, x); break;
        case 2: v0 = fetch<4, 22   >(ptrs.p[4],  e, y, x);
                v1 = fetch<5, 11   >(ptrs.p[5],  e, y, x); break;
        case 3: v0 = fetch<1, 176  >(ptrs.p[6],  e, y, x);
                v1 = fetch<2, 88   >(ptrs.p[7],  e, y, x); break;
        case 4: v0 = fetch<3, 44   >(ptrs.p[8],  e, y, x);
                v1 = fetch<4, 22   >(ptrs.p[9],  e, y, x); break;
        default: v0 = fetch<5, 11  >(ptrs.p[10], e, y, x);
                 v1 = fetch<1, 176 >(ptrs.p[11], e, y, x); break;
    }

    float* base = out + g * 2 * PLANE + e;
    *reinterpret_cast<float4*>(base)         = v0;
    *reinterpret_cast<float4*>(base + PLANE) = v1;
}

extern "C" void kernel_launch(void* const* d_in, const int* in_sizes, int n_in,
                              void* d_out, int out_size, void* d_ws, size_t ws_size,
                              hipStream_t stream) {
    Ptrs ptrs;
    for (int i = 0; i < 12; ++i) ptrs.p[i] = (const float*)d_in[i];
    float* out = (float*)d_out;

    // plane float4 count = 123904/4 = 30976 = 121 * 256; 6 groups of 2 channels
    dim3 grid(121, 6);
    resize_cat_kernel<<<grid, 256, 0, stream>>>(ptrs, out);
}